// Round 4
// baseline (47.150 us; speedup 1.0000x reference)
//
#include <hip/hip_runtime.h>

// LMHT neuron with multi-level positive/negative quantization.
// x: [T=8, B=64, N=65536] fp32; v_threshold: [1] fp32.
// Per neuron (flattened B*N): v += x[t]; k = trunc(clamp(v/th, -4, 4));
// out[t] = k*th; v -= out[t].
// Memory-bound: 128 MiB in + 128 MiB out -> ~43 us floor at 6.3 TB/s.

constexpr int   kT = 8;
constexpr float kL = 4.0f;

__device__ __forceinline__ float quant_pn(float v, float th) {
    float k = v / th;                       // true IEEE div; matches jnp semantics
    k = fminf(fmaxf(k, -kL), kL);           // clamp to [-L, L]
    k = truncf(k);                          // floor-toward-zero == where(k>0,floor)+where(k<0,ceil)
    return k * th;
}

__global__ __launch_bounds__(256) void lmht_pn_kernel(
    const float4* __restrict__ x,
    const float*  __restrict__ vth,
    float4* __restrict__ out,
    int n4)   // (B*N)/4 float4 elements per timestep
{
    const float th = vth[0];
    const int idx    = blockIdx.x * blockDim.x + threadIdx.x;
    const int stride = gridDim.x * blockDim.x;

    for (int i = idx; i < n4; i += stride) {
        float4 v = make_float4(0.0f, 0.0f, 0.0f, 0.0f);
        #pragma unroll
        for (int t = 0; t < kT; ++t) {
            // Loads are independent of the v-chain -> compiler can hoist all 8
            // global_load_dwordx4 up front for max memory-level parallelism.
            float4 xt = x[(size_t)t * (size_t)n4 + (size_t)i];
            float4 o;
            v.x += xt.x;  o.x = quant_pn(v.x, th);  v.x -= o.x;
            v.y += xt.y;  o.y = quant_pn(v.y, th);  v.y -= o.y;
            v.z += xt.z;  o.z = quant_pn(v.z, th);  v.z -= o.z;
            v.w += xt.w;  o.w = quant_pn(v.w, th);  v.w -= o.w;
            out[(size_t)t * (size_t)n4 + (size_t)i] = o;
        }
    }
}

extern "C" void kernel_launch(void* const* d_in, const int* in_sizes, int n_in,
                              void* d_out, int out_size, void* d_ws, size_t ws_size,
                              hipStream_t stream) {
    const float* x   = (const float*)d_in[0];
    const float* vth = (const float*)d_in[1];
    float*       out = (float*)d_out;

    // in_sizes[0] = T*B*N; per-timestep element count = total / T.
    const int total = in_sizes[0];
    const int bn    = total / kT;
    const int n4    = bn / 4;   // B*N = 4,194,304 -> n4 = 1,048,576

    const int block = 256;
    int grid = (n4 + block - 1) / block;
    if (grid > 2048) grid = 2048;           // 8 blocks/CU; grid-stride covers the rest

    lmht_pn_kernel<<<grid, block, 0, stream>>>(
        (const float4*)x, vth, (float4*)out, n4);
}

// Round 6
// 46.663 us; speedup vs baseline: 1.0104x; 1.0104x over previous
//
#include <hip/hip_runtime.h>

// LMHT neuron with multi-level positive/negative quantization.
// x: [T=8, B=64, N=65536] fp32; v_threshold: [1] fp32.
// Per neuron (flattened B*N): v += x[t]; k = trunc(clamp(v/th, -4, 4));
// out[t] = k*th; v -= out[t].
// Memory-bound. R4 baseline: 47.15 us, FETCH 64 MiB (L3 partial residency),
// WRITE 128 MiB. This round: non-temporal stores (via native clang vector
// type — HIP_vector_type float4 is rejected by the builtin) so the
// write-once output doesn't evict x from L3.

constexpr int   kT = 8;
constexpr float kL = 4.0f;

typedef float f32x4 __attribute__((ext_vector_type(4)));

__device__ __forceinline__ float quant_pn(float v, float th) {
    float k = v / th;                       // true IEEE div; matches jnp semantics
    k = fminf(fmaxf(k, -kL), kL);           // clamp to [-L, L]
    k = truncf(k);                          // floor-toward-zero == where(k>0,floor)+where(k<0,ceil)
    return k * th;
}

__global__ __launch_bounds__(256) void lmht_pn_kernel(
    const f32x4* __restrict__ x,
    const float* __restrict__ vth,
    f32x4* __restrict__ out,
    int n4)   // (B*N)/4 float4 elements per timestep
{
    const float th = vth[0];
    const int idx    = blockIdx.x * blockDim.x + threadIdx.x;
    const int stride = gridDim.x * blockDim.x;

    for (int i = idx; i < n4; i += stride) {
        f32x4 v = (f32x4)(0.0f);
        #pragma unroll
        for (int t = 0; t < kT; ++t) {
            // Loads are independent of the v-chain -> compiler hoists all 8
            // global_load_dwordx4 up front for max memory-level parallelism.
            f32x4 xt = x[(size_t)t * (size_t)n4 + (size_t)i];
            f32x4 o;
            v.x += xt.x;  o.x = quant_pn(v.x, th);  v.x -= o.x;
            v.y += xt.y;  o.y = quant_pn(v.y, th);  v.y -= o.y;
            v.z += xt.z;  o.z = quant_pn(v.z, th);  v.z -= o.z;
            v.w += xt.w;  o.w = quant_pn(v.w, th);  v.w -= o.w;
            // Write-once stream: non-temporal store so out doesn't evict x
            // from the 256 MiB L3.
            __builtin_nontemporal_store(o, &out[(size_t)t * (size_t)n4 + (size_t)i]);
        }
    }
}

extern "C" void kernel_launch(void* const* d_in, const int* in_sizes, int n_in,
                              void* d_out, int out_size, void* d_ws, size_t ws_size,
                              hipStream_t stream) {
    const float* x   = (const float*)d_in[0];
    const float* vth = (const float*)d_in[1];
    float*       out = (float*)d_out;

    // in_sizes[0] = T*B*N; per-timestep element count = total / T.
    const int total = in_sizes[0];
    const int bn    = total / kT;
    const int n4    = bn / 4;   // B*N = 4,194,304 -> n4 = 1,048,576

    const int block = 256;
    int grid = (n4 + block - 1) / block;    // 4096 blocks: 1 float4/thread,
                                            // one 8-deep independent load chain each
    lmht_pn_kernel<<<grid, block, 0, stream>>>(
        (const f32x4*)x, vth, (f32x4*)out, n4);
}

// Round 7
// 44.576 us; speedup vs baseline: 1.0578x; 1.0468x over previous
//
#include <hip/hip_runtime.h>

// LMHT neuron with multi-level positive/negative quantization.
// x: [T=8, B=64, N=65536] fp32; v_threshold: [1] fp32.
// Per neuron (flattened B*N): v += x[t]; k = trunc(clamp(v/th, -4, 4));
// out[t] = k*th; v -= out[t].
// Memory-bound. R4: 47.15 us baseline (FETCH 65.5 MB / WRITE 131 MB).
// R6: __builtin_nontemporal_store (nt flag) = neutral, FETCH unchanged ->
// bare nt does not steer L3 write allocation. This round: inline-asm store
// with full scope flags `sc0 sc1 nt` (system-scope streaming store) to try
// to keep the write-once output stream from evicting x out of the 256 MiB
// Infinity Cache.

constexpr int   kT = 8;
constexpr float kL = 4.0f;

typedef float f32x4 __attribute__((ext_vector_type(4)));

__device__ __forceinline__ float quant_pn(float v, float th) {
    float k = v / th;                       // true IEEE div; matches jnp semantics
    k = fminf(fmaxf(k, -kL), kL);           // clamp to [-L, L]
    k = truncf(k);                          // floor-toward-zero == where(k>0,floor)+where(k<0,ceil)
    return k * th;
}

__device__ __forceinline__ void store_stream(f32x4* p, f32x4 v) {
    // System-scope non-temporal store: sc0 sc1 nt. Goal: no L2/L3 allocation
    // for the write-once output stream.
    asm volatile("global_store_dwordx4 %0, %1, off sc0 sc1 nt"
                 :: "v"(p), "v"(v) : "memory");
}

__global__ __launch_bounds__(256) void lmht_pn_kernel(
    const f32x4* __restrict__ x,
    const float* __restrict__ vth,
    f32x4* __restrict__ out,
    int n4)   // (B*N)/4 float4 elements per timestep
{
    const float th = vth[0];
    const int idx    = blockIdx.x * blockDim.x + threadIdx.x;
    const int stride = gridDim.x * blockDim.x;

    for (int i = idx; i < n4; i += stride) {
        f32x4 v = (f32x4)(0.0f);
        #pragma unroll
        for (int t = 0; t < kT; ++t) {
            // Loads are independent of the v-chain -> compiler hoists all 8
            // global_load_dwordx4 up front for max memory-level parallelism.
            f32x4 xt = x[(size_t)t * (size_t)n4 + (size_t)i];
            f32x4 o;
            v.x += xt.x;  o.x = quant_pn(v.x, th);  v.x -= o.x;
            v.y += xt.y;  o.y = quant_pn(v.y, th);  v.y -= o.y;
            v.z += xt.z;  o.z = quant_pn(v.z, th);  v.z -= o.z;
            v.w += xt.w;  o.w = quant_pn(v.w, th);  v.w -= o.w;
            store_stream(&out[(size_t)t * (size_t)n4 + (size_t)i], o);
        }
    }
}

extern "C" void kernel_launch(void* const* d_in, const int* in_sizes, int n_in,
                              void* d_out, int out_size, void* d_ws, size_t ws_size,
                              hipStream_t stream) {
    const float* x   = (const float*)d_in[0];
    const float* vth = (const float*)d_in[1];
    float*       out = (float*)d_out;

    // in_sizes[0] = T*B*N; per-timestep element count = total / T.
    const int total = in_sizes[0];
    const int bn    = total / kT;
    const int n4    = bn / 4;   // B*N = 4,194,304 -> n4 = 1,048,576

    const int block = 256;
    int grid = (n4 + block - 1) / block;    // 4096 blocks: 1 float4/thread,
                                            // one 8-deep independent load chain each
    lmht_pn_kernel<<<grid, block, 0, stream>>>(
        (const f32x4*)x, vth, (f32x4*)out, n4);
}